// Round 6
// baseline (78.656 us; speedup 1.0000x reference)
//
#include <hip/hip_runtime.h>

// QLinear: y[n,o] = round((sum_k (x[n,k]-xz)*(w[o,k]-wz) + bias[o]) * M + yz)
// N=65536, K=512, OUT=512.
// Exact i8 path: (x-128),(w-128) in [-128,127]; |dot+bias| < 2^24; f32 epilogue exact.
// R6: full-width tiles (64 rows x 512 cols per block) -> x f32 read EXACTLY once.
//     A: reg-staged (distance 2) -> i8 -> tiny fragment-major LDS (2 x 4KB).
//     B: fragment-direct global loads from L2-resident W_i8 (no LDS).
//     Raw s_barrier + lgkmcnt(0) only -- A-loads stay in flight across barriers.

#define K_DIM 512
#define OUTF  512
#define NT    8            // K_DIM / 64

typedef __attribute__((ext_vector_type(4))) int   i32x4;
typedef __attribute__((ext_vector_type(4))) float f32x4;
typedef __attribute__((ext_vector_type(2))) unsigned int u32x2;

// ---------- prepass: weight int32 -> i8 (w - wz), row-major [o][k] ----------
__global__ void wprep(const int* __restrict__ W, unsigned int* __restrict__ Wb,
                      const float* __restrict__ wzp) {
    const int wz = __float2int_rn(wzp[0]);
    int idx = (blockIdx.x * blockDim.x + threadIdx.x) * 4;
    i32x4 w = *reinterpret_cast<const i32x4*>(W + idx);
    unsigned int p = ((unsigned int)(w[0] - wz) & 0xffu)
                   | (((unsigned int)(w[1] - wz) & 0xffu) << 8)
                   | (((unsigned int)(w[2] - wz) & 0xffu) << 16)
                   | (((unsigned int)(w[3] - wz) & 0xffu) << 24);
    Wb[idx >> 2] = p;
}

__global__ __launch_bounds__(512, 4)
void qgemm(const float* __restrict__ X,
           const unsigned char* __restrict__ Wb,
           const int* __restrict__ bias,
           const float* __restrict__ Mp,
           const float* __restrict__ xzp,
           const float* __restrict__ yzp,
           float* __restrict__ Y) {
    // A tile only, i8, fragment-major: frag m (rows m*16..+15) at m*1024,
    // element (lane l, 16B) = row (l&15), k-bytes (l>>4)*16. Double-buffered.
    __shared__ unsigned char lds[2][4096];

    const int tid  = threadIdx.x;
    const int lane = tid & 63;
    const int wid  = tid >> 6;               // 0..7 -> col strip 64*wid
    const int fr   = lane & 15;
    const int fq   = lane >> 4;

    const int row0 = blockIdx.x * 64;
    const int c0   = wid * 64;

    const float xzf = xzp[0];

    // stage map: thread -> row tid>>3 (0..63), k-offset (tid&7)*8 (8 f32)
    const int srow = tid >> 3;
    const int sk   = (tid & 7) * 8;
    const float* xbase = X + (size_t)(row0 + srow) * K_DIM + sk;
    // LDS dest: frag = srow>>4; lane-slot = (srow&15) + (sk>>4)*16; half = sk&8
    const int ldst = (srow >> 4) * 1024 + ((srow & 15) + ((sk >> 4) << 4)) * 16 + (sk & 8);

    f32x4 ra[2][2];                           // two staging sets, 8 f32 each

    auto stageA = [&](int t, int s) {
        const float* p = xbase + t * 64;
        ra[s][0] = *reinterpret_cast<const f32x4*>(p);
        ra[s][1] = *reinterpret_cast<const f32x4*>(p + 4);
    };
    auto convwrite = [&](int buf, int s) {
        u32x2 v;
        #pragma unroll
        for (int h = 0; h < 2; ++h) {
            unsigned int u0 = (unsigned int)((int)(ra[s][h][0] - xzf)) & 0xffu;
            unsigned int u1 = (unsigned int)((int)(ra[s][h][1] - xzf)) & 0xffu;
            unsigned int u2 = (unsigned int)((int)(ra[s][h][2] - xzf)) & 0xffu;
            unsigned int u3 = (unsigned int)((int)(ra[s][h][3] - xzf)) & 0xffu;
            v[h] = u0 | (u1 << 8) | (u2 << 16) | (u3 << 24);
        }
        *reinterpret_cast<u32x2*>(&lds[buf][ldst]) = v;
    };

    // bias folded into accumulator init; acc[m][n]: rows m*16, cols n*16
    i32x4 acc[4][4];
    #pragma unroll
    for (int n = 0; n < 4; ++n) {
        const int bv = bias[c0 + n * 16 + fr];
        #pragma unroll
        for (int m = 0; m < 4; ++m)
            acc[m][n] = i32x4{bv, bv, bv, bv};
    }

    // B fragment-direct: col = c0 + n*16 + fr, k-bytes fq*16 (+ ks*64)
    const unsigned char* wbb = Wb + (size_t)(c0 + fr) * K_DIM + fq * 16;

    auto compute = [&](int buf, int ks) {
        i32x4 af[4], bf[4];
        #pragma unroll
        for (int m = 0; m < 4; ++m)
            af[m] = *reinterpret_cast<const i32x4*>(&lds[buf][m * 1024 + lane * 16]);
        #pragma unroll
        for (int n = 0; n < 4; ++n)
            bf[n] = *reinterpret_cast<const i32x4*>(wbb + (size_t)n * 16 * K_DIM + ks * 64);
        #pragma unroll
        for (int m = 0; m < 4; ++m)
            #pragma unroll
            for (int n = 0; n < 4; ++n)
                acc[m][n] = __builtin_amdgcn_mfma_i32_16x16x64_i8(
                    af[m], bf[n], acc[m][n], 0, 0, 0);
    };

    auto barrier = [&]() {
        asm volatile("s_waitcnt lgkmcnt(0)" ::: "memory");   // drain only LDS ops
        __builtin_amdgcn_s_barrier();
    };

    // prologue: t=0,1 loads in flight; write t=0 (waits only its own regs)
    stageA(0, 0);
    stageA(1, 1);
    convwrite(0, 0);
    barrier();

    #pragma unroll
    for (int t = 0; t < NT; ++t) {
        if (t + 2 < NT) stageA(t + 2, t & 1);               // far-ahead issue first
        compute(t & 1, t);
        if (t + 1 < NT) convwrite((t + 1) & 1, (t + 1) & 1); // consume 1-iter-old loads
        barrier();
    }

    // epilogue: y = rintf(acc * M + yz)  (bias pre-folded)
    const float Mv = Mp[0], yz = yzp[0];
    #pragma unroll
    for (int n = 0; n < 4; ++n) {
        const int col = c0 + n * 16 + fr;
        #pragma unroll
        for (int m = 0; m < 4; ++m) {
            const int row = row0 + m * 16 + fq * 4;
            float* yp = Y + (size_t)row * OUTF + col;
            #pragma unroll
            for (int j = 0; j < 4; ++j)
                yp[(size_t)j * OUTF] = rintf((float)acc[m][n][j] * Mv + yz);
        }
    }
}

extern "C" void kernel_launch(void* const* d_in, const int* in_sizes, int n_in,
                              void* d_out, int out_size, void* d_ws, size_t ws_size,
                              hipStream_t stream) {
    const float* x    = (const float*)d_in[0];
    const int*   w    = (const int*)d_in[1];
    const int*   bias = (const int*)d_in[2];
    const float* M    = (const float*)d_in[3];
    const float* xz   = (const float*)d_in[4];
    const float* wz   = (const float*)d_in[5];
    const float* yz   = (const float*)d_in[6];
    float* y = (float*)d_out;

    unsigned int* Wb = (unsigned int*)d_ws;     // 512*512 i8 = 256 KB

    wprep<<<256, 256, 0, stream>>>(w, Wb, wz);
    qgemm<<<1024, 512, 0, stream>>>(x, (const unsigned char*)Wb, bias, M, xz, yz, y);
}